// Round 12
// baseline (1093.563 us; speedup 1.0000x reference)
//
#include <hip/hip_runtime.h>
#include <cstddef>
#include <cstdint>

#define B_ 512
#define T_ 2048
#define I_ 16
#define H_ 40

typedef __fp16 half_t;
typedef half_t h2 __attribute__((ext_vector_type(2)));
typedef half_t h8 __attribute__((ext_vector_type(8)));
typedef float f4 __attribute__((ext_vector_type(4)));

// tanh(x) = 1 - 2/(exp(2x)+1); exp(2x) = exp2(x * 2*log2(e)).
__device__ __forceinline__ float fast_tanh(float x) {
  float e = __builtin_amdgcn_exp2f(x * 2.8853900817779268f);
  return 1.0f - 2.0f * __builtin_amdgcn_rcpf(e + 1.0f);
}
// v_dot2_f32_f16: 2 fp16 MACs, f32 accumulate.
__device__ __forceinline__ float dot2(h2 a, h2 b, float c) {
  return __builtin_amdgcn_fdot2(a, b, c, false);
}
// Use-site fp16 pack (volatile: pins the vmcnt wait at use-site, r9-proven).
__device__ __forceinline__ h2 cvtpk_v(float lo, float hi) {
  h2 r;
  asm volatile("v_cvt_pkrtz_f16_f32 %0, %1, %2" : "=v"(r) : "v"(lo), "v"(hi));
  return r;
}
#define PIN(v) asm volatile("" : "+v"(v))

// ASYNC x prefetch via volatile asm (r9-proven decoupling). 64B = one step.
#define GLOADQ(R0, R1, R2, R3, P)                                   \
  asm volatile("global_load_dwordx4 %0, %4, off\n\t"                \
               "global_load_dwordx4 %1, %4, off offset:16\n\t"      \
               "global_load_dwordx4 %2, %4, off offset:32\n\t"      \
               "global_load_dwordx4 %3, %4, off offset:48"          \
               : "=&v"(R0), "=&v"(R1), "=&v"(R2), "=&v"(R3)         \
               : "v"(P))
#define WAITX(N) asm volatile("s_waitcnt vmcnt(" #N ")")

// Pack one f32 weight row into resident half2 VGPRs.
#define LOADW(DST, SRC, STR, N2)                                    \
  _Pragma("unroll") for (int k = 0; k < (N2); ++k) {                \
    DST[k][0] = (half_t)SRC[jr * (STR) + 2 * k];                    \
    DST[k][1] = (half_t)SRC[jr * (STR) + 2 * k + 1];                \
    PIN(DST[k]);                                                    \
  }

// Register h broadcast (r10-proven) + optional LDS publish for the next wave:
// dpp(XOR-1) -> even lane 2p holds pack(h[2p],h[2p+1]) -> masked ds_write of
// compacted pairs (consumer side) + 20 readlanes (local recurrent side).
#define BCAST_PUB(NH, PAIRS, PUB, PH, LY) do {                      \
  int nb_ = __builtin_amdgcn_update_dpp(                            \
      0, __builtin_bit_cast(int, (NH)), 0xB1, 0xf, 0xf, false);     \
  h2 pk_ = __builtin_amdgcn_cvt_pkrtz((NH),                         \
      __builtin_bit_cast(float, nb_));                              \
  int pkb_ = __builtin_bit_cast(int, pk_);                          \
  if (PUB) {                                                        \
    if (((lane) & 1) == 0 && (lane) < H_)                           \
      hbuf[PH][LY][(lane) >> 1] = (unsigned)pkb_;                   \
  }                                                                 \
  _Pragma("unroll") for (int p = 0; p < H_ / 2; ++p)                \
    PAIRS[p] = __builtin_bit_cast(h2,                               \
        __builtin_amdgcn_readlane(pkb_, 2 * p));                    \
} while (0)

// 20 dot2 against local uniform pairs.
#define HDS(PAIRS, W, A0, A1, A2, A3)                               \
  _Pragma("unroll") for (int p = 0; p < 5; ++p) {                   \
    A0 = dot2(PAIRS[4 * p + 0], (W)[4 * p + 0], A0);                \
    A1 = dot2(PAIRS[4 * p + 1], (W)[4 * p + 1], A1);                \
    A2 = dot2(PAIRS[4 * p + 2], (W)[4 * p + 2], A2);                \
    A3 = dot2(PAIRS[4 * p + 3], (W)[4 * p + 3], A3);                \
  }

// 20 dot2 against 5 preloaded h8 (uniform LDS reads; extracts are free).
#define HDQ(Q, W, A0, A1, A2, A3)                                   \
  _Pragma("unroll") for (int m = 0; m < 5; ++m) {                   \
    h2 p0 = {Q[m][0], Q[m][1]}, p1 = {Q[m][2], Q[m][3]};            \
    h2 p2 = {Q[m][4], Q[m][5]}, p3 = {Q[m][6], Q[m][7]};            \
    A0 = dot2(p0, (W)[4 * m + 0], A0);                              \
    A1 = dot2(p1, (W)[4 * m + 1], A1);                              \
    A2 = dot2(p2, (W)[4 * m + 2], A2);                              \
    A3 = dot2(p3, (W)[4 * m + 3], A3);                              \
  }

#define PACKX(XH, R0, R1, R2, R3)                                   \
  do {                                                              \
    XH[0] = cvtpk_v(R0[0], R0[1]); XH[1] = cvtpk_v(R0[2], R0[3]);   \
    XH[2] = cvtpk_v(R1[0], R1[1]); XH[3] = cvtpk_v(R1[2], R1[3]);   \
    XH[4] = cvtpk_v(R2[0], R2[1]); XH[5] = cvtpk_v(R2[2], R2[3]);   \
    XH[6] = cvtpk_v(R3[0], R3[1]); XH[7] = cvtpk_v(R3[2], R3[3]);   \
  } while (0)

// wave0 tick: h0[u] = tanh(w0i*x[u] + w0h*h0[u-1]); publish pairs to hbuf[PH][0].
#define TICK_A(R0, R1, R2, R3, PH, TNEXT) do {                      \
  WAITX(4);                                                         \
  PACKX(xh, R0, R1, R2, R3);                                        \
  float a0 = bias0, a1 = 0.f, a2 = 0.f, a3 = 0.f;                   \
  a0 = dot2(xh[0], w0i[0], a0); a1 = dot2(xh[1], w0i[1], a1);       \
  a2 = dot2(xh[2], w0i[2], a2); a3 = dot2(xh[3], w0i[3], a3);       \
  a0 = dot2(xh[4], w0i[4], a0); a1 = dot2(xh[5], w0i[5], a1);       \
  a2 = dot2(xh[6], w0i[6], a2); a3 = dot2(xh[7], w0i[7], a3);       \
  HDS(hpA, w0h, a0, a1, a2, a3);                                    \
  float nh0 = fast_tanh((a0 + a1) + (a2 + a3));                     \
  BCAST_PUB(nh0, hpA, 1, PH, 0);                                    \
  { const float* pf_ = xb +                                         \
        (size_t)(((TNEXT) < T_) ? (TNEXT) : (T_ - 1)) * I_;         \
    GLOADQ(R0, R1, R2, R3, pf_); }                                  \
} while (0)

// wave1 tick: h1[u-1] = tanh(w1i*h0[u-1] + w1h*h1[u-2]).
// h0 from hbuf[PHR][0] (5 uniform reads, hidden under the 20 local w1h dots);
// h1 recur kept locally (readlane pairs). Publishes h1 pairs to hbuf[PH][1].
#define TICK_B(PH, PHR) do {                                        \
  h8 q[5];                                                          \
  { const h8* hq_ = (const h8*)&hbuf[PHR][0][0];                    \
    _Pragma("unroll") for (int m = 0; m < 5; ++m) q[m] = hq_[m]; }  \
  float b0v = bias1, b1v = 0.f, b2v = 0.f, b3v = 0.f;               \
  HDS(hpB, w1h, b0v, b1v, b2v, b3v);                                \
  HDQ(q, w1i, b0v, b1v, b2v, b3v);                                  \
  float nh1 = fast_tanh((b0v + b1v) + (b2v + b3v));                 \
  BCAST_PUB(nh1, hpB, 1, PH, 1);                                    \
} while (0)

// wave2 tick: h2[u-2] = tanh(w2i*h1[u-2] + w2h*h2[u-3]). No publish.
#define TICK_C(PHR) do {                                            \
  h8 q[5];                                                          \
  { const h8* hq_ = (const h8*)&hbuf[PHR][1][0];                    \
    _Pragma("unroll") for (int m = 0; m < 5; ++m) q[m] = hq_[m]; }  \
  float c0v = bias2, c1v = 0.f, c2v = 0.f, c3v = 0.f;               \
  HDS(hpC, w2h, c0v, c1v, c2v, c3v);                                \
  HDQ(q, w2i, c0v, c1v, c2v, c3v);                                  \
  nh2v = fast_tanh((c0v + c1v) + (c2v + c3v));                      \
  BCAST_PUB(nh2v, hpC, 0, 0, 0);                                    \
} while (0)

__global__ __launch_bounds__(192)
__attribute__((amdgpu_waves_per_eu(2, 2)))  // 256-reg cap, 2 blocks/CU
void rnn3_fused(const float* __restrict__ x,
                const float* __restrict__ wih0, const float* __restrict__ whh0,
                const float* __restrict__ bih0, const float* __restrict__ bhh0,
                const float* __restrict__ wih1, const float* __restrict__ whh1,
                const float* __restrict__ b_ih1, const float* __restrict__ bhh1,
                const float* __restrict__ wih2, const float* __restrict__ whh2,
                const float* __restrict__ bih2, const float* __restrict__ bhh2,
                const float* __restrict__ fcw, const float* __restrict__ fcb,
                float* __restrict__ out) {
  const int b = blockIdx.x;
  const int lane = threadIdx.x & 63;
  const int wv = threadIdx.x >> 6;          // 0: layer0+x, 1: layer1, 2: layer2+FC
  const int jr = (lane < H_) ? lane : (H_ - 1);

  // ping-pong h-pair buffers: [parity][layer(0=h0,1=h1)][20 u32 pairs] (+pad)
  __shared__ __align__(16) unsigned hbuf[2][2][24];

  h2 w0i[8], w0h[20], w1i[20], w1h[20], w2i[20], w2h[20];
  h2 hpA[20], hpB[20], hpC[20];
  float bias0 = 0.f, bias1 = 0.f, bias2 = 0.f;
  f4 rA0, rA1, rA2, rA3, rB0, rB1, rB2, rB3;
  h2 xh[8];
  float nh2v = 0.f;
  const float* __restrict__ xb = x + (size_t)b * (T_ * I_);

  if (wv == 0) {
    LOADW(w0i, wih0, I_, 8)
    LOADW(w0h, whh0, H_, 20)
    bias0 = bih0[jr] + bhh0[jr]; PIN(bias0);
#pragma unroll
    for (int p = 0; p < 20; ++p) hpA[p] = h2{(half_t)0.f, (half_t)0.f};
    GLOADQ(rA0, rA1, rA2, rA3, xb);        // x[0]
    GLOADQ(rB0, rB1, rB2, rB3, xb + I_);   // x[1]
  } else if (wv == 1) {
    LOADW(w1i, wih1, H_, 20)
    LOADW(w1h, whh1, H_, 20)
    bias1 = b_ih1[jr] + bhh1[jr]; PIN(bias1);
#pragma unroll
    for (int p = 0; p < 20; ++p) hpB[p] = h2{(half_t)0.f, (half_t)0.f};
  } else {
    LOADW(w2i, wih2, H_, 20)
    LOADW(w2h, whh2, H_, 20)
    bias2 = bih2[jr] + bhh2[jr]; PIN(bias2);
#pragma unroll
    for (int p = 0; p < 20; ++p) hpC[p] = h2{(half_t)0.f, (half_t)0.f};
  }
  __syncthreads();

  // ---- skew prologue ----
  if (wv == 0) TICK_A(rA0, rA1, rA2, rA3, 0, 2);         // tick 0: h0[0]
  __syncthreads();
  if (wv == 0)      TICK_A(rB0, rB1, rB2, rB3, 1, 3);    // tick 1: h0[1]
  else if (wv == 1) TICK_B(1, 0);                        //         h1[0]
  __syncthreads();

  // ---- steady state: ticks 2..2047 (all three waves active) ----
  for (int u = 2; u < T_; u += 2) {
    if (wv == 0)      TICK_A(rA0, rA1, rA2, rA3, 0, u + 2);
    else if (wv == 1) TICK_B(0, 1);
    else              TICK_C(1);
    __syncthreads();
    if (wv == 0)      TICK_A(rB0, rB1, rB2, rB3, 1, u + 3);
    else if (wv == 1) TICK_B(1, 0);
    else              TICK_C(0);
    __syncthreads();
  }

  // ---- epilogue: tick 2048 (B computes h1[2047], C h2[2046]) ----
  if (wv == 0) {
    asm volatile("s_waitcnt vmcnt(0)");    // drain async x loads
    PIN(rA0); PIN(rA1); PIN(rA2); PIN(rA3);
    PIN(rB0); PIN(rB1); PIN(rB2); PIN(rB3);
  } else if (wv == 1) {
    TICK_B(0, 1);
  } else {
    TICK_C(1);
  }
  __syncthreads();

  // ---- tick 2049: C computes h2[2047]; FC head ----
  if (wv == 2) {
    TICK_C(0);
    const float fw = (lane < H_) ? fcw[lane] : 0.f;
    float v = nh2v * fw;
#pragma unroll
    for (int off = 32; off > 0; off >>= 1) v += __shfl_down(v, off);
    if (lane == 0) out[b] = v + fcb[0];
  }
}

extern "C" void kernel_launch(void* const* d_in, const int* in_sizes, int n_in,
                              void* d_out, int out_size, void* d_ws, size_t ws_size,
                              hipStream_t stream) {
  (void)in_sizes; (void)n_in; (void)d_ws; (void)ws_size; (void)out_size;
  const float* x    = (const float*)d_in[0];
  const float* wih0 = (const float*)d_in[1];
  const float* whh0 = (const float*)d_in[2];
  const float* bih0 = (const float*)d_in[3];
  const float* bhh0 = (const float*)d_in[4];
  const float* wih1 = (const float*)d_in[5];
  const float* whh1 = (const float*)d_in[6];
  const float* bih1 = (const float*)d_in[7];
  const float* bhh1 = (const float*)d_in[8];
  const float* wih2 = (const float*)d_in[9];
  const float* whh2 = (const float*)d_in[10];
  const float* bih2 = (const float*)d_in[11];
  const float* bhh2 = (const float*)d_in[12];
  const float* fcw  = (const float*)d_in[13];
  const float* fcb  = (const float*)d_in[14];
  float* out = (float*)d_out;

  hipLaunchKernelGGL(rnn3_fused, dim3(B_), dim3(192), 0, stream,
                     x, wih0, whh0, bih0, bhh0,
                     wih1, whh1, bih1, bhh1,
                     wih2, whh2, bih2, bhh2,
                     fcw, fcb, out);
}